// Round 1
// baseline (649.593 us; speedup 1.0000x reference)
//
#include <hip/hip_runtime.h>
#include <cstdint>

#define MDIM 4096
#define NDIM 9216
#define KDIM 3072
#define KP   3136   // 3072 + 32 lora + 32 zero pad = 49 tiles of 64
#define NKT  49

typedef unsigned int u32;
typedef unsigned short u16;
typedef float f32x4 __attribute__((ext_vector_type(4)));
typedef __bf16 bf16x8 __attribute__((ext_vector_type(8)));

__device__ __forceinline__ u16 f2bf(float f) {
  u32 u = __float_as_uint(f);
  u32 r = u + 0x7fffu + ((u >> 16) & 1u);   // round-to-nearest-even
  return (u16)(r >> 16);
}

__device__ __forceinline__ void gld_lds16(const void* g, void* l) {
  __builtin_amdgcn_global_load_lds((__attribute__((address_space(1))) void*)g,
                                   (__attribute__((address_space(3))) void*)l,
                                   16, 0, 0);
}

// ---------------- kernel 1: activation smooth + group quant + lora_act ----------------
// one block per row m; writes A_ext row (KP bf16): [0,3072) = deq, [3072,3104) = lora_act, rest 0
__global__ void k_quant(const float* __restrict__ x, const float* __restrict__ smooth,
                        const float* __restrict__ lora_down, u16* __restrict__ Aex) {
  __shared__ float xs_s[KDIM];
  __shared__ float part[8][32];
  const int m = blockIdx.x;
  const int tid = threadIdx.x;
  const int sub = tid & 15;
  const float* xr = x + (size_t)m * KDIM;
  u16* arow = Aex + (size_t)m * KP;

  #pragma unroll
  for (int p = 0; p < 3; ++p) {
    int g = p * 16 + (tid >> 4);
    int k0 = g * 64 + sub * 4;
    float4 xv = *(const float4*)(xr + k0);
    float4 sv = *(const float4*)(smooth + k0);
    float a0 = xv.x / sv.x, a1 = xv.y / sv.y, a2 = xv.z / sv.z, a3 = xv.w / sv.w;
    xs_s[k0+0] = a0; xs_s[k0+1] = a1; xs_s[k0+2] = a2; xs_s[k0+3] = a3;
    float am = fmaxf(fmaxf(fabsf(a0), fabsf(a1)), fmaxf(fabsf(a2), fabsf(a3)));
    am = fmaxf(am, __shfl_xor(am, 8, 16));
    am = fmaxf(am, __shfl_xor(am, 4, 16));
    am = fmaxf(am, __shfl_xor(am, 2, 16));
    am = fmaxf(am, __shfl_xor(am, 1, 16));
    float asc = fmaxf(am * (1.0f / 7.0f) , 1e-8f);
    // match ref: ascale = max/7 (true division), then clamp
    asc = fmaxf(am / 7.0f, 1e-8f);
    float q0 = fminf(7.f, fmaxf(-8.f, rintf(a0 / asc)));
    float q1 = fminf(7.f, fmaxf(-8.f, rintf(a1 / asc)));
    float q2 = fminf(7.f, fmaxf(-8.f, rintf(a2 / asc)));
    float q3 = fminf(7.f, fmaxf(-8.f, rintf(a3 / asc)));
    float d0 = q0 * asc, d1 = q1 * asc, d2 = q2 * asc, d3 = q3 * asc;
    u32 lo = (u32)f2bf(d0) | ((u32)f2bf(d1) << 16);
    u32 hi = (u32)f2bf(d2) | ((u32)f2bf(d3) << 16);
    *(uint2*)(arow + k0) = make_uint2(lo, hi);
  }
  if (tid < 32) arow[3104 + tid] = 0;   // zero pad tail
  __syncthreads();
  // lora_act[m][r] = sum_k xs[k] * lora_down[k][r]
  {
    int chunk = tid >> 5, r = tid & 31;
    float s = 0.f;
    int kb = chunk * 384;
    #pragma unroll 8
    for (int i = 0; i < 384; ++i)
      s += xs_s[kb + i] * lora_down[(size_t)(kb + i) * 32 + r];
    part[chunk][r] = s;
  }
  __syncthreads();
  if (tid < 32) {
    float s = 0.f;
    #pragma unroll
    for (int c = 0; c < 8; ++c) s += part[c][tid];
    arow[3072 + tid] = f2bf(s);   // LORA_SCALE = 1.0
  }
}

// ---------------- kernel 1b: detect qweight storage layout ----------------
// flag=1 : each original int8 stored as a sign-extended int32 ; flag=0 : raw int8 bytes
__global__ void k_detect(const u32* __restrict__ qw, int* __restrict__ flag) {
  __shared__ int viol;
  if (threadIdx.x == 0) viol = 0;
  __syncthreads();
  u32 w = qw[threadIdx.x];
  u32 s = (w & 0x80u) ? 0xffffff00u : 0u;
  if ((w & 0xffffff00u) != s) atomicAdd(&viol, 1);
  __syncthreads();
  if (threadIdx.x == 0) *flag = (viol == 0) ? 1 : 0;
}

// ---------------- kernel 2: weight int4 dequant -> B_ext bf16 ----------------
// thread handles 4 packed bytes = 8 weights (one 16B bf16 store), all within one group
__global__ void k_wdq(const u32* __restrict__ qw, const float* __restrict__ wsc,
                      u16* __restrict__ Bex, const int* __restrict__ flag) {
  const int f = *flag;
  int idx = blockIdx.x * 256 + threadIdx.x;   // < 9216*384
  int n = idx / 384;
  int j = idx - n * 384;
  int k0 = j * 8;
  u32 w;
  if (f) {
    const int* q32 = (const int*)qw;
    int base = n * 1536 + j * 4;
    w  = (u32)(q32[base + 0] & 0xff);
    w |= (u32)(q32[base + 1] & 0xff) << 8;
    w |= (u32)(q32[base + 2] & 0xff) << 16;
    w |= (u32)(q32[base + 3] & 0xff) << 24;
  } else {
    w = qw[idx];
  }
  float ws = wsc[(k0 >> 6) * NDIM + n];
  u32 ow[4];
  #pragma unroll
  for (int b = 0; b < 4; ++b) {
    int by = (int)((w >> (8 * b)) & 0xffu);
    int lo = (by << 28) >> 28;   // low nibble, sign-extended (k even)
    int hi = (by << 24) >> 28;   // high nibble, sign-extended (k odd)
    ow[b] = (u32)f2bf((float)lo * ws) | ((u32)f2bf((float)hi * ws) << 16);
  }
  *(uint4*)(Bex + (size_t)n * KP + k0) = make_uint4(ow[0], ow[1], ow[2], ow[3]);
}

// ---------------- kernel 2b: B_ext lora columns + pad ----------------
__global__ void k_bpad(const float* __restrict__ lora_up, u16* __restrict__ Bex) {
  int idx = blockIdx.x * 256 + threadIdx.x;  // < 9216*64
  int n = idx >> 6, c = idx & 63;
  u16 v = 0;
  if (c < 32) v = f2bf(lora_up[n * 32 + c]);
  Bex[(size_t)n * KP + 3072 + c] = v;
}

// ---------------- kernel 3: bf16 MFMA GEMM, C = A_ext * B_ext^T + bias ----------------
// block tile 128x128, BK=64, 4 waves, each wave 64x64 via 4x4 of 16x16x32 MFMA
__global__ __launch_bounds__(256) void k_gemm(const u16* __restrict__ A, const u16* __restrict__ B,
                                              const float* __restrict__ bias, float* __restrict__ out) {
  __shared__ __align__(16) u16 sA[128 * 64];
  __shared__ __align__(16) u16 sB[128 * 64];
  const int tid  = threadIdx.x;
  const int lane = tid & 63;
  const int wave = tid >> 6;
  const int m0 = blockIdx.y * 128;
  const int n0 = blockIdx.x * 128;
  const int wm = (wave >> 1) * 64;
  const int wn = (wave & 1) * 64;
  const int lr = lane & 15;
  const int lq = lane >> 4;

  f32x4 acc[4][4] = {};

  // staging descriptors: LDS chunk p holds global 16B-chunk (r, (p&7)^(r&7))  [xor swizzle]
  const u16* ga[4]; const u16* gb[4]; u16* la[4]; u16* lb[4];
  #pragma unroll
  for (int i = 0; i < 4; ++i) {
    int p = i * 256 + tid;
    int r = p >> 3;
    int c = (p & 7) ^ (r & 7);
    ga[i] = A + (size_t)(m0 + r) * KP + c * 8;
    gb[i] = B + (size_t)(n0 + r) * KP + c * 8;
    la[i] = &sA[p * 8];
    lb[i] = &sB[p * 8];
  }
  // LDS read offsets (constant over K loop)
  int aoff[2][4], boff[2][4];
  #pragma unroll
  for (int ks = 0; ks < 2; ++ks) {
    int cch = lq + ks * 4;
    #pragma unroll
    for (int t = 0; t < 4; ++t) {
      int rowa = wm + t * 16 + lr;
      int rowb = wn + t * 16 + lr;
      aoff[ks][t] = rowa * 64 + ((cch ^ (rowa & 7)) * 8);
      boff[ks][t] = rowb * 64 + ((cch ^ (rowb & 7)) * 8);
    }
  }

  for (int kt = 0; kt < NKT; ++kt) {
    #pragma unroll
    for (int i = 0; i < 4; ++i) { gld_lds16(ga[i], la[i]); ga[i] += 64; }
    #pragma unroll
    for (int i = 0; i < 4; ++i) { gld_lds16(gb[i], lb[i]); gb[i] += 64; }
    asm volatile("s_waitcnt vmcnt(0)" ::: "memory");
    __syncthreads();
    #pragma unroll
    for (int ks = 0; ks < 2; ++ks) {
      bf16x8 af[4], bf[4];
      #pragma unroll
      for (int t = 0; t < 4; ++t) af[t] = *(const bf16x8*)&sA[aoff[ks][t]];
      #pragma unroll
      for (int t = 0; t < 4; ++t) bf[t] = *(const bf16x8*)&sB[boff[ks][t]];
      #pragma unroll
      for (int ti = 0; ti < 4; ++ti)
        #pragma unroll
        for (int tj = 0; tj < 4; ++tj)
          acc[ti][tj] = __builtin_amdgcn_mfma_f32_16x16x32_bf16(af[ti], bf[tj], acc[ti][tj], 0, 0, 0);
    }
    __syncthreads();
  }

  // epilogue: + bias, store fp32.  C/D layout: col = lane&15, row = (lane>>4)*4 + reg
  #pragma unroll
  for (int tj = 0; tj < 4; ++tj) {
    int n = n0 + wn + tj * 16 + lr;
    float bv = bias[n];
    #pragma unroll
    for (int ti = 0; ti < 4; ++ti) {
      int mrow = m0 + wm + ti * 16 + lq * 4;
      #pragma unroll
      for (int rg = 0; rg < 4; ++rg)
        out[(size_t)(mrow + rg) * NDIM + n] = acc[ti][tj][rg] + bv;
    }
  }
}

// ---------------- kernel 4: in-place RMSNorm (q,k) + RoPE ----------------
// one wave per (m, head, q/k); v rows untouched
__global__ void k_normrope(float* __restrict__ out, const float* __restrict__ norm_q,
                           const float* __restrict__ norm_k, const float* __restrict__ rot) {
  int item = blockIdx.x * 4 + (threadIdx.x >> 6);
  int lane = threadIdx.x & 63;
  int m = item / 48;
  int h = item - m * 48;
  int sel = h / 24;            // 0 = q, 1 = k
  int head = h - sel * 24;
  float* p = out + (size_t)m * NDIM + sel * 3072 + head * 128;
  float2 eo = ((float2*)p)[lane];
  float ss = eo.x * eo.x + eo.y * eo.y;
  #pragma unroll
  for (int off = 32; off > 0; off >>= 1) ss += __shfl_xor(ss, off, 64);
  float sc = rsqrtf(ss * (1.0f / 128.0f) + 1e-6f);
  const float2* nrm = (const float2*)(sel ? norm_k : norm_q);
  float2 g = nrm[lane];
  float e = eo.x * sc * g.x;
  float o = eo.y * sc * g.y;
  float2 cs = ((const float2*)rot)[m * 64 + lane];
  float2 res;
  res.x = e * cs.x - o * cs.y;
  res.y = e * cs.y + o * cs.x;
  ((float2*)p)[lane] = res;
}

extern "C" void kernel_launch(void* const* d_in, const int* in_sizes, int n_in,
                              void* d_out, int out_size, void* d_ws, size_t ws_size,
                              hipStream_t stream) {
  const float* x         = (const float*)d_in[0];
  const u32*   qweight   = (const u32*)d_in[1];
  const float* wscales   = (const float*)d_in[2];
  const float* bias      = (const float*)d_in[3];
  const float* lora_down = (const float*)d_in[4];
  const float* lora_up   = (const float*)d_in[5];
  const float* smooth    = (const float*)d_in[6];
  const float* norm_q    = (const float*)d_in[7];
  const float* norm_k    = (const float*)d_in[8];
  const float* rot       = (const float*)d_in[9];
  float* out = (float*)d_out;

  u16* Aex = (u16*)d_ws;                               // 4096*3136 bf16
  u16* Bex = Aex + (size_t)MDIM * KP;                  // 9216*3136 bf16
  int* flag = (int*)(Bex + (size_t)NDIM * KP);         // 4 bytes

  k_detect<<<1, 256, 0, stream>>>(qweight, flag);
  k_quant<<<MDIM, 256, 0, stream>>>(x, smooth, lora_down, Aex);
  k_wdq<<<(NDIM * 384) / 256, 256, 0, stream>>>(qweight, wscales, Bex, flag);
  k_bpad<<<(NDIM * 64) / 256, 256, 0, stream>>>(lora_up, Bex);
  k_gemm<<<dim3(NDIM / 128, MDIM / 128), 256, 0, stream>>>(Aex, Bex, bias, out);
  k_normrope<<<(MDIM * 48) / 4, 256, 0, stream>>>(out, norm_q, norm_k, rot);
}

// Round 2
// 608.810 us; speedup vs baseline: 1.0670x; 1.0670x over previous
//
#include <hip/hip_runtime.h>
#include <cstdint>

#define MDIM 4096
#define NDIM 9216
#define KDIM 3072
#define KP   3136   // 3072 + 32 lora + 32 zero pad = 49 tiles of 64
#define NKT  49

typedef unsigned int u32;
typedef unsigned short u16;
typedef float f32x4 __attribute__((ext_vector_type(4)));
typedef __bf16 bf16x8 __attribute__((ext_vector_type(8)));

__device__ __forceinline__ u16 f2bf(float f) {
  u32 u = __float_as_uint(f);
  u32 r = u + 0x7fffu + ((u >> 16) & 1u);   // round-to-nearest-even
  return (u16)(r >> 16);
}

__device__ __forceinline__ float frcp(float f) { return __builtin_amdgcn_rcpf(f); }

__device__ __forceinline__ void gld_lds16(const void* g, void* l) {
  __builtin_amdgcn_global_load_lds((__attribute__((address_space(1))) void*)g,
                                   (__attribute__((address_space(3))) void*)l,
                                   16, 0, 0);
}

// ---------------- kernel 1: activation smooth + group quant + lora_act ----------------
// one block per row m; writes A_ext row (KP bf16): [0,3072) = deq, [3072,3104) = lora_act, rest 0
__global__ __launch_bounds__(256) void k_quant(const float* __restrict__ x, const float* __restrict__ smooth,
                        const float* __restrict__ lora_down, u16* __restrict__ Aex) {
  __shared__ float xs_s[KDIM];
  __shared__ float part[8][32];
  const int m = blockIdx.x;
  const int tid = threadIdx.x;
  const int sub = tid & 15;
  const float* xr = x + (size_t)m * KDIM;
  u16* arow = Aex + (size_t)m * KP;

  #pragma unroll
  for (int p = 0; p < 3; ++p) {
    int g = p * 16 + (tid >> 4);
    int k0 = g * 64 + sub * 4;
    float4 xv = *(const float4*)(xr + k0);
    float4 sv = *(const float4*)(smooth + k0);
    float a0 = xv.x * frcp(sv.x), a1 = xv.y * frcp(sv.y);
    float a2 = xv.z * frcp(sv.z), a3 = xv.w * frcp(sv.w);
    xs_s[k0+0] = a0; xs_s[k0+1] = a1; xs_s[k0+2] = a2; xs_s[k0+3] = a3;
    float am = fmaxf(fmaxf(fabsf(a0), fabsf(a1)), fmaxf(fabsf(a2), fabsf(a3)));
    am = fmaxf(am, __shfl_xor(am, 8, 16));
    am = fmaxf(am, __shfl_xor(am, 4, 16));
    am = fmaxf(am, __shfl_xor(am, 2, 16));
    am = fmaxf(am, __shfl_xor(am, 1, 16));
    float asc = fmaxf(am * (1.0f / 7.0f), 1e-8f);
    float iasc = frcp(asc);
    float q0 = fminf(7.f, fmaxf(-8.f, rintf(a0 * iasc)));
    float q1 = fminf(7.f, fmaxf(-8.f, rintf(a1 * iasc)));
    float q2 = fminf(7.f, fmaxf(-8.f, rintf(a2 * iasc)));
    float q3 = fminf(7.f, fmaxf(-8.f, rintf(a3 * iasc)));
    float d0 = q0 * asc, d1 = q1 * asc, d2 = q2 * asc, d3 = q3 * asc;
    u32 lo = (u32)f2bf(d0) | ((u32)f2bf(d1) << 16);
    u32 hi = (u32)f2bf(d2) | ((u32)f2bf(d3) << 16);
    *(uint2*)(arow + k0) = make_uint2(lo, hi);
  }
  if (tid < 32) arow[3104 + tid] = 0;   // zero pad tail
  __syncthreads();
  // lora_act[m][r] = sum_k xs[k] * lora_down[k][r]
  {
    int chunk = tid >> 5, r = tid & 31;
    float s = 0.f;
    int kb = chunk * 384;
    #pragma unroll 8
    for (int i = 0; i < 384; ++i)
      s += xs_s[kb + i] * lora_down[(size_t)(kb + i) * 32 + r];
    part[chunk][r] = s;
  }
  __syncthreads();
  if (tid < 32) {
    float s = 0.f;
    #pragma unroll
    for (int c = 0; c < 8; ++c) s += part[c][tid];
    arow[3072 + tid] = f2bf(s);   // LORA_SCALE = 1.0
  }
}

// ---------------- kernel 2: weight int4 dequant -> B_ext bf16 (+ lora cols / pad) ----------------
// blocks [0, 13824): dequant, thread = 4 packed bytes = 8 weights (16B bf16 store)
// blocks [13824, 16128): fill Bex[:, 3072:3136) = lora_up | 0
#define DQ_BLOCKS 13824
__global__ __launch_bounds__(256) void k_wdq(const u32* __restrict__ qw, const float* __restrict__ wsc,
                      const float* __restrict__ lora_up, u16* __restrict__ Bex) {
  const int tid = threadIdx.x;
  if (blockIdx.x >= DQ_BLOCKS) {
    int idx = (blockIdx.x - DQ_BLOCKS) * 256 + tid;  // < 9216*64
    int n = idx >> 6, c = idx & 63;
    u16 v = 0;
    if (c < 32) v = f2bf(lora_up[n * 32 + c]);
    Bex[(size_t)n * KP + 3072 + c] = v;
    return;
  }
  // per-block layout detect: int8 stored as sign-extended int32 (f=1) vs raw bytes (f=0)
  __shared__ int s_viol;
  u32 probe = qw[tid];
  bool ok = (probe >> 8) == ((probe & 0x80u) ? 0xffffffu : 0u);
  if (tid == 0) s_viol = 0;
  __syncthreads();
  if (!ok) atomicOr(&s_viol, 1);
  __syncthreads();
  const int f = (s_viol == 0);

  int idx = blockIdx.x * 256 + tid;   // < 9216*384
  int n = idx / 384;
  int j = idx - n * 384;
  int k0 = j * 8;
  u32 w;
  if (f) {
    uint4 q4 = ((const uint4*)qw)[idx];          // 4 sign-extended int32s, coalesced 16B
    w  = (q4.x & 0xffu) | ((q4.y & 0xffu) << 8) | ((q4.z & 0xffu) << 16) | ((q4.w & 0xffu) << 24);
  } else {
    w = qw[idx];
  }
  float ws = wsc[(k0 >> 6) * NDIM + n];
  u32 ow[4];
  #pragma unroll
  for (int b = 0; b < 4; ++b) {
    int by = (int)((w >> (8 * b)) & 0xffu);
    int lo = (by << 28) >> 28;   // low nibble (k even)
    int hi = (by << 24) >> 28;   // high nibble (k odd)
    ow[b] = (u32)f2bf((float)lo * ws) | ((u32)f2bf((float)hi * ws) << 16);
  }
  *(uint4*)(Bex + (size_t)n * KP + k0) = make_uint4(ow[0], ow[1], ow[2], ow[3]);
}

// ---------------- kernel 3: bf16 MFMA GEMM + fused bias / RMSNorm / RoPE epilogue ----------------
// block tile 128x128 (one head per block column), BK=64, 4 waves, wave 64x64 via 4x4 of 16x16x32
__global__ __launch_bounds__(256) void k_gemm(const u16* __restrict__ A, const u16* __restrict__ B,
                                              const float* __restrict__ bias, const float* __restrict__ norm_q,
                                              const float* __restrict__ norm_k, const float* __restrict__ rot,
                                              float* __restrict__ out) {
  __shared__ __align__(16) u16 sA[128 * 64];
  __shared__ __align__(16) u16 sB[128 * 64];
  const int tid  = threadIdx.x;
  const int lane = tid & 63;
  const int wave = tid >> 6;
  const int m0 = blockIdx.y * 128;
  const int n0 = blockIdx.x * 128;
  const int wm = (wave >> 1) * 64;
  const int wn = (wave & 1) * 64;
  const int lr = lane & 15;
  const int lq = lane >> 4;

  f32x4 acc[4][4] = {};

  // staging: LDS chunk p holds global 16B-chunk (r, (p&7)^(r&7))  [xor swizzle]
  const u16* ga[4]; const u16* gb[4]; u16* la[4]; u16* lb[4];
  #pragma unroll
  for (int i = 0; i < 4; ++i) {
    int p = i * 256 + tid;
    int r = p >> 3;
    int c = (p & 7) ^ (r & 7);
    ga[i] = A + (size_t)(m0 + r) * KP + c * 8;
    gb[i] = B + (size_t)(n0 + r) * KP + c * 8;
    la[i] = &sA[p * 8];
    lb[i] = &sB[p * 8];
  }
  int aoff[2][4], boff[2][4];
  #pragma unroll
  for (int ks = 0; ks < 2; ++ks) {
    int cch = lq + ks * 4;
    #pragma unroll
    for (int t = 0; t < 4; ++t) {
      int rowa = wm + t * 16 + lr;
      int rowb = wn + t * 16 + lr;
      aoff[ks][t] = rowa * 64 + ((cch ^ (rowa & 7)) * 8);
      boff[ks][t] = rowb * 64 + ((cch ^ (rowb & 7)) * 8);
    }
  }

  for (int kt = 0; kt < NKT; ++kt) {
    #pragma unroll
    for (int i = 0; i < 4; ++i) { gld_lds16(ga[i], la[i]); ga[i] += 64; }
    #pragma unroll
    for (int i = 0; i < 4; ++i) { gld_lds16(gb[i], lb[i]); gb[i] += 64; }
    asm volatile("s_waitcnt vmcnt(0)" ::: "memory");
    __syncthreads();
    #pragma unroll
    for (int ks = 0; ks < 2; ++ks) {
      bf16x8 af[4], bf[4];
      #pragma unroll
      for (int t = 0; t < 4; ++t) af[t] = *(const bf16x8*)&sA[aoff[ks][t]];
      #pragma unroll
      for (int t = 0; t < 4; ++t) bf[t] = *(const bf16x8*)&sB[boff[ks][t]];
      #pragma unroll
      for (int ti = 0; ti < 4; ++ti)
        #pragma unroll
        for (int tj = 0; tj < 4; ++tj)
          acc[ti][tj] = __builtin_amdgcn_mfma_f32_16x16x32_bf16(af[ti], bf[tj], acc[ti][tj], 0, 0, 0);
    }
    __syncthreads();
  }

  // ---- epilogue.  C/D layout: col = lane&15, row = (lane>>4)*4 + reg ----
  // block column == one head (128 cols): sel 0=q 1=k 2=v
  const int sel = (n0 >= 6144) ? 2 : ((n0 >= 3072) ? 1 : 0);

  // bias (in-place into acc)
  #pragma unroll
  for (int tj = 0; tj < 4; ++tj) {
    float bv = bias[n0 + wn + tj * 16 + lr];
    #pragma unroll
    for (int ti = 0; ti < 4; ++ti)
      #pragma unroll
      for (int rg = 0; rg < 4; ++rg)
        acc[ti][tj][rg] += bv;
  }

  if (sel == 2) {
    #pragma unroll
    for (int tj = 0; tj < 4; ++tj) {
      int n = n0 + wn + tj * 16 + lr;
      #pragma unroll
      for (int ti = 0; ti < 4; ++ti) {
        int mrow = m0 + wm + ti * 16 + lq * 4;
        #pragma unroll
        for (int rg = 0; rg < 4; ++rg)
          out[(size_t)(mrow + rg) * NDIM + n] = acc[ti][tj][rg];
      }
    }
    return;
  }

  // RMSNorm: per-row sum of squares over the 128 head cols
  float part[4][4];
  #pragma unroll
  for (int ti = 0; ti < 4; ++ti)
    #pragma unroll
    for (int rg = 0; rg < 4; ++rg) {
      float s = 0.f;
      #pragma unroll
      for (int tj = 0; tj < 4; ++tj) s += acc[ti][tj][rg] * acc[ti][tj][rg];
      part[ti][rg] = s;
    }
  #pragma unroll
  for (int off = 1; off < 16; off <<= 1)
    #pragma unroll
    for (int ti = 0; ti < 4; ++ti)
      #pragma unroll
      for (int rg = 0; rg < 4; ++rg)
        part[ti][rg] += __shfl_xor(part[ti][rg], off);

  float* ssq = (float*)sA;   // [2][128]: [wn half][block-local row] — sA dead after last barrier
  #pragma unroll
  for (int ti = 0; ti < 4; ++ti)
    #pragma unroll
    for (int rg = 0; rg < 4; ++rg)
      if (lr == ti * 4 + rg)
        ssq[(wn >> 6) * 128 + wm + ti * 16 + lq * 4 + rg] = part[ti][rg];
  __syncthreads();

  const float* nrm = sel ? norm_k : norm_q;
  float gm[4];
  #pragma unroll
  for (int tj = 0; tj < 4; ++tj) gm[tj] = nrm[wn + tj * 16 + lr];
  const float2* rot2 = (const float2*)rot;
  const float sgn = (lr & 1) ? 1.0f : -1.0f;

  #pragma unroll
  for (int ti = 0; ti < 4; ++ti) {
    #pragma unroll
    for (int rg = 0; rg < 4; ++rg) {
      int row = wm + ti * 16 + lq * 4 + rg;
      float tot = ssq[row] + ssq[128 + row];
      float rs = rsqrtf(tot * (1.0f / 128.0f) + 1e-6f);
      int m = m0 + row;
      #pragma unroll
      for (int tj = 0; tj < 4; ++tj) {
        int nl = wn + tj * 16 + lr;                 // block-local col = head dim index
        float v = acc[ti][tj][rg] * rs * gm[tj];
        float p = __shfl_xor(v, 1);                 // partner (other half of rope pair, same row)
        float2 cs = rot2[(size_t)m * 64 + (nl >> 1)];
        // even col: v*cos - p*sin ; odd col: p*sin ... -> v*cos + sgn*p*sin
        float r = v * cs.x + sgn * (p * cs.y);
        out[(size_t)m * NDIM + n0 + nl] = r;
      }
    }
  }
}

extern "C" void kernel_launch(void* const* d_in, const int* in_sizes, int n_in,
                              void* d_out, int out_size, void* d_ws, size_t ws_size,
                              hipStream_t stream) {
  const float* x         = (const float*)d_in[0];
  const u32*   qweight   = (const u32*)d_in[1];
  const float* wscales   = (const float*)d_in[2];
  const float* bias      = (const float*)d_in[3];
  const float* lora_down = (const float*)d_in[4];
  const float* lora_up   = (const float*)d_in[5];
  const float* smooth    = (const float*)d_in[6];
  const float* norm_q    = (const float*)d_in[7];
  const float* norm_k    = (const float*)d_in[8];
  const float* rot       = (const float*)d_in[9];
  float* out = (float*)d_out;

  u16* Aex = (u16*)d_ws;                               // 4096*3136 bf16
  u16* Bex = Aex + (size_t)MDIM * KP;                  // 9216*3136 bf16

  k_quant<<<MDIM, 256, 0, stream>>>(x, smooth, lora_down, Aex);
  k_wdq<<<DQ_BLOCKS + (NDIM * 64) / 256, 256, 0, stream>>>(qweight, wscales, lora_up, Bex);
  k_gemm<<<dim3(NDIM / 128, MDIM / 128), 256, 0, stream>>>(Aex, Bex, bias, norm_q, norm_k, rot, out);
}

// Round 3
// 596.721 us; speedup vs baseline: 1.0886x; 1.0203x over previous
//
#include <hip/hip_runtime.h>
#include <cstdint>

#define MDIM 4096
#define NDIM 9216
#define KDIM 3072
#define KP   3136   // 3072 + 32 lora + 32 zero pad = 49 tiles of 64
#define NKT  49

#define QB 4096            // quant blocks (one row each)
#define WB 13824           // weight-dequant blocks
#define PB 2304            // B-pad blocks (9216*64/256)

typedef unsigned int u32;
typedef unsigned short u16;
typedef float f32x4 __attribute__((ext_vector_type(4)));
typedef __bf16 bf16x8 __attribute__((ext_vector_type(8)));

__device__ __forceinline__ u16 f2bf(float f) {
  u32 u = __float_as_uint(f);
  u32 r = u + 0x7fffu + ((u >> 16) & 1u);   // round-to-nearest-even
  return (u16)(r >> 16);
}

__device__ __forceinline__ float frcp(float f) { return __builtin_amdgcn_rcpf(f); }

__device__ __forceinline__ void gld_lds16(const void* g, void* l) {
  __builtin_amdgcn_global_load_lds((__attribute__((address_space(1))) void*)g,
                                   (__attribute__((address_space(3))) void*)l,
                                   16, 0, 0);
}

// ---------------- kernel 1: fused prep ----------------
// blocks [0,QB): per-row activation smooth+quant+lora_act -> Aex row
// blocks [QB,QB+WB): int4 weight dequant -> Bex
// blocks [QB+WB,QB+WB+PB): Bex lora columns + zero pad
__global__ __launch_bounds__(256) void k_prep(const float* __restrict__ x, const u32* __restrict__ qw,
                        const float* __restrict__ wsc, const float* __restrict__ lora_down,
                        const float* __restrict__ lora_up, const float* __restrict__ smooth,
                        u16* __restrict__ Aex, u16* __restrict__ Bex) {
  __shared__ float xs_s[KDIM];        // 12 KB
  __shared__ float part[64 * 32];     // 8 KB  [chunk][rank]
  const int tid = threadIdx.x;
  int bid = blockIdx.x;

  if (bid >= QB) {
    bid -= QB;
    if (bid >= WB) {
      // ---- pad path: Bex[:, 3072:3136) = lora_up | 0 ----
      int idx = (bid - WB) * 256 + tid;        // < 9216*64
      int n = idx >> 6, c = idx & 63;
      u16 v = 0;
      if (c < 32) v = f2bf(lora_up[n * 32 + c]);
      Bex[(size_t)n * KP + 3072 + c] = v;
      return;
    }
    // ---- weight dequant path ----
    // per-block layout detect: int8 stored as sign-extended int32 (f=1) vs raw bytes (f=0)
    __shared__ int s_viol;
    u32 probe = qw[tid];
    bool ok = (probe >> 8) == ((probe & 0x80u) ? 0xffffffu : 0u);
    if (tid == 0) s_viol = 0;
    __syncthreads();
    if (!ok) atomicOr(&s_viol, 1);
    __syncthreads();
    const int f = (s_viol == 0);

    int idx = bid * 256 + tid;   // < 9216*384
    int n = idx / 384;
    int j = idx - n * 384;
    int k0 = j * 8;
    u32 w;
    if (f) {
      uint4 q4 = ((const uint4*)qw)[idx];      // 4 sign-extended int32s, coalesced 16B
      w = (q4.x & 0xffu) | ((q4.y & 0xffu) << 8) | ((q4.z & 0xffu) << 16) | ((q4.w & 0xffu) << 24);
    } else {
      w = qw[idx];
    }
    float ws = wsc[(k0 >> 6) * NDIM + n];
    u32 ow[4];
    #pragma unroll
    for (int b = 0; b < 4; ++b) {
      int by = (int)((w >> (8 * b)) & 0xffu);
      int lo = (by << 28) >> 28;   // low nibble (k even)
      int hi = (by << 24) >> 28;   // high nibble (k odd)
      ow[b] = (u32)f2bf((float)lo * ws) | ((u32)f2bf((float)hi * ws) << 16);
    }
    *(uint4*)(Bex + (size_t)n * KP + k0) = make_uint4(ow[0], ow[1], ow[2], ow[3]);
    return;
  }

  // ---- quant path: one row m = bid ----
  const int m = bid;
  const int sub = tid & 15;
  const float* xr = x + (size_t)m * KDIM;
  u16* arow = Aex + (size_t)m * KP;

  #pragma unroll
  for (int p = 0; p < 3; ++p) {
    int g = p * 16 + (tid >> 4);
    int k0 = g * 64 + sub * 4;
    float4 xv = *(const float4*)(xr + k0);
    float4 sv = *(const float4*)(smooth + k0);
    float a0 = xv.x * frcp(sv.x), a1 = xv.y * frcp(sv.y);
    float a2 = xv.z * frcp(sv.z), a3 = xv.w * frcp(sv.w);
    xs_s[k0+0] = a0; xs_s[k0+1] = a1; xs_s[k0+2] = a2; xs_s[k0+3] = a3;
    float am = fmaxf(fmaxf(fabsf(a0), fabsf(a1)), fmaxf(fabsf(a2), fabsf(a3)));
    am = fmaxf(am, __shfl_xor(am, 8, 16));
    am = fmaxf(am, __shfl_xor(am, 4, 16));
    am = fmaxf(am, __shfl_xor(am, 2, 16));
    am = fmaxf(am, __shfl_xor(am, 1, 16));
    float asc = fmaxf(am * (1.0f / 7.0f), 1e-8f);
    float iasc = frcp(asc);
    float q0 = fminf(7.f, fmaxf(-8.f, rintf(a0 * iasc)));
    float q1 = fminf(7.f, fmaxf(-8.f, rintf(a1 * iasc)));
    float q2 = fminf(7.f, fmaxf(-8.f, rintf(a2 * iasc)));
    float q3 = fminf(7.f, fmaxf(-8.f, rintf(a3 * iasc)));
    float d0 = q0 * asc, d1 = q1 * asc, d2 = q2 * asc, d3 = q3 * asc;
    u32 lo = (u32)f2bf(d0) | ((u32)f2bf(d1) << 16);
    u32 hi = (u32)f2bf(d2) | ((u32)f2bf(d3) << 16);
    *(uint2*)(arow + k0) = make_uint2(lo, hi);
  }
  if (tid < 32) arow[3104 + tid] = 0;   // zero pad tail
  __syncthreads();

  // lora_act[r] = sum_k xs[k] * lora_down[k][r]
  // thread = (chunk c = tid>>2 of 64, ranks r8..r8+7 where r8=(tid&3)*8)
  // k = i*64 + c  (interleaved chunking: LDS reads conflict-free w/ immediate
  // offsets; wave's 16 consecutive k-rows = 2 KB contiguous global reads)
  {
    const int c  = tid >> 2;
    const int r8 = (tid & 3) * 8;
    float a[8] = {0.f, 0.f, 0.f, 0.f, 0.f, 0.f, 0.f, 0.f};
    const float* lp = lora_down + (size_t)c * 32 + r8;   // advance 64*32 floats per i
    #pragma unroll 4
    for (int i = 0; i < 48; ++i) {
      float xv = xs_s[i * 64 + c];
      float4 l0 = *(const float4*)(lp);
      float4 l1 = *(const float4*)(lp + 4);
      a[0] = fmaf(xv, l0.x, a[0]); a[1] = fmaf(xv, l0.y, a[1]);
      a[2] = fmaf(xv, l0.z, a[2]); a[3] = fmaf(xv, l0.w, a[3]);
      a[4] = fmaf(xv, l1.x, a[4]); a[5] = fmaf(xv, l1.y, a[5]);
      a[6] = fmaf(xv, l1.z, a[6]); a[7] = fmaf(xv, l1.w, a[7]);
      lp += 64 * 32;
    }
    __syncthreads();   // xs_s reads done before part overlays nothing; ordering only
    *(float4*)(&part[c * 32 + r8])     = make_float4(a[0], a[1], a[2], a[3]);
    *(float4*)(&part[c * 32 + r8 + 4]) = make_float4(a[4], a[5], a[6], a[7]);
  }
  __syncthreads();
  if (tid < 32) {
    float s = 0.f;
    #pragma unroll 8
    for (int cc = 0; cc < 64; ++cc) s += part[cc * 32 + tid];
    arow[3072 + tid] = f2bf(s);   // LORA_SCALE = 1.0
  }
}

// ---------------- kernel 2: bf16 MFMA GEMM + fused bias / RMSNorm / RoPE epilogue ----------------
// block tile 128x128 (one head per block column), BK=64, 4 waves, wave 64x64 via 4x4 of 16x16x32
__global__ __launch_bounds__(256) void k_gemm(const u16* __restrict__ A, const u16* __restrict__ B,
                                              const float* __restrict__ bias, const float* __restrict__ norm_q,
                                              const float* __restrict__ norm_k, const float* __restrict__ rot,
                                              float* __restrict__ out) {
  __shared__ __align__(16) u16 sA[128 * 64];
  __shared__ __align__(16) u16 sB[128 * 64];
  const int tid  = threadIdx.x;
  const int lane = tid & 63;
  const int wave = tid >> 6;
  const int m0 = blockIdx.y * 128;
  const int n0 = blockIdx.x * 128;
  const int wm = (wave >> 1) * 64;
  const int wn = (wave & 1) * 64;
  const int lr = lane & 15;
  const int lq = lane >> 4;

  f32x4 acc[4][4] = {};

  // staging: LDS chunk p holds global 16B-chunk (r, (p&7)^(r&7))  [xor swizzle]
  const u16* ga[4]; const u16* gb[4]; u16* la[4]; u16* lb[4];
  #pragma unroll
  for (int i = 0; i < 4; ++i) {
    int p = i * 256 + tid;
    int r = p >> 3;
    int c = (p & 7) ^ (r & 7);
    ga[i] = A + (size_t)(m0 + r) * KP + c * 8;
    gb[i] = B + (size_t)(n0 + r) * KP + c * 8;
    la[i] = &sA[p * 8];
    lb[i] = &sB[p * 8];
  }
  int aoff[2][4], boff[2][4];
  #pragma unroll
  for (int ks = 0; ks < 2; ++ks) {
    int cch = lq + ks * 4;
    #pragma unroll
    for (int t = 0; t < 4; ++t) {
      int rowa = wm + t * 16 + lr;
      int rowb = wn + t * 16 + lr;
      aoff[ks][t] = rowa * 64 + ((cch ^ (rowa & 7)) * 8);
      boff[ks][t] = rowb * 64 + ((cch ^ (rowb & 7)) * 8);
    }
  }

  for (int kt = 0; kt < NKT; ++kt) {
    #pragma unroll
    for (int i = 0; i < 4; ++i) { gld_lds16(ga[i], la[i]); ga[i] += 64; }
    #pragma unroll
    for (int i = 0; i < 4; ++i) { gld_lds16(gb[i], lb[i]); gb[i] += 64; }
    asm volatile("s_waitcnt vmcnt(0)" ::: "memory");
    __syncthreads();
    #pragma unroll
    for (int ks = 0; ks < 2; ++ks) {
      bf16x8 af[4], bf[4];
      #pragma unroll
      for (int t = 0; t < 4; ++t) af[t] = *(const bf16x8*)&sA[aoff[ks][t]];
      #pragma unroll
      for (int t = 0; t < 4; ++t) bf[t] = *(const bf16x8*)&sB[boff[ks][t]];
      #pragma unroll
      for (int ti = 0; ti < 4; ++ti)
        #pragma unroll
        for (int tj = 0; tj < 4; ++tj)
          acc[ti][tj] = __builtin_amdgcn_mfma_f32_16x16x32_bf16(af[ti], bf[tj], acc[ti][tj], 0, 0, 0);
    }
    __syncthreads();
  }

  // ---- epilogue.  C/D layout: col = lane&15, row = (lane>>4)*4 + reg ----
  // block column == one head (128 cols): sel 0=q 1=k 2=v
  const int sel = (n0 >= 6144) ? 2 : ((n0 >= 3072) ? 1 : 0);

  #pragma unroll
  for (int tj = 0; tj < 4; ++tj) {
    float bv = bias[n0 + wn + tj * 16 + lr];
    #pragma unroll
    for (int ti = 0; ti < 4; ++ti)
      #pragma unroll
      for (int rg = 0; rg < 4; ++rg)
        acc[ti][tj][rg] += bv;
  }

  if (sel == 2) {
    #pragma unroll
    for (int tj = 0; tj < 4; ++tj) {
      int n = n0 + wn + tj * 16 + lr;
      #pragma unroll
      for (int ti = 0; ti < 4; ++ti) {
        int mrow = m0 + wm + ti * 16 + lq * 4;
        #pragma unroll
        for (int rg = 0; rg < 4; ++rg)
          out[(size_t)(mrow + rg) * NDIM + n] = acc[ti][tj][rg];
      }
    }
    return;
  }

  // RMSNorm: per-row sum of squares over the 128 head cols
  float part[4][4];
  #pragma unroll
  for (int ti = 0; ti < 4; ++ti)
    #pragma unroll
    for (int rg = 0; rg < 4; ++rg) {
      float s = 0.f;
      #pragma unroll
      for (int tj = 0; tj < 4; ++tj) s += acc[ti][tj][rg] * acc[ti][tj][rg];
      part[ti][rg] = s;
    }
  #pragma unroll
  for (int off = 1; off < 16; off <<= 1)
    #pragma unroll
    for (int ti = 0; ti < 4; ++ti)
      #pragma unroll
      for (int rg = 0; rg < 4; ++rg)
        part[ti][rg] += __shfl_xor(part[ti][rg], off);

  float* ssq = (float*)sA;   // [2][128]: [wn half][block-local row] — sA dead after last barrier
  #pragma unroll
  for (int ti = 0; ti < 4; ++ti)
    #pragma unroll
    for (int rg = 0; rg < 4; ++rg)
      if (lr == ti * 4 + rg)
        ssq[(wn >> 6) * 128 + wm + ti * 16 + lq * 4 + rg] = part[ti][rg];
  __syncthreads();

  const float* nrm = sel ? norm_k : norm_q;
  float gm[4];
  #pragma unroll
  for (int tj = 0; tj < 4; ++tj) gm[tj] = nrm[wn + tj * 16 + lr];
  const float2* rot2 = (const float2*)rot;
  const float sgn = (lr & 1) ? 1.0f : -1.0f;

  #pragma unroll
  for (int ti = 0; ti < 4; ++ti) {
    #pragma unroll
    for (int rg = 0; rg < 4; ++rg) {
      int row = wm + ti * 16 + lq * 4 + rg;
      float tot = ssq[row] + ssq[128 + row];
      float rs = rsqrtf(tot * (1.0f / 128.0f) + 1e-6f);
      int m = m0 + row;
      #pragma unroll
      for (int tj = 0; tj < 4; ++tj) {
        int nl = wn + tj * 16 + lr;                 // block-local col = head dim index
        float v = acc[ti][tj][rg] * rs * gm[tj];
        float p = __shfl_xor(v, 1);                 // rope partner (same row, col^1)
        float2 cs = rot2[(size_t)m * 64 + (nl >> 1)];
        float r = v * cs.x + sgn * (p * cs.y);
        out[(size_t)m * NDIM + n0 + nl] = r;
      }
    }
  }
}

extern "C" void kernel_launch(void* const* d_in, const int* in_sizes, int n_in,
                              void* d_out, int out_size, void* d_ws, size_t ws_size,
                              hipStream_t stream) {
  const float* x         = (const float*)d_in[0];
  const u32*   qweight   = (const u32*)d_in[1];
  const float* wscales   = (const float*)d_in[2];
  const float* bias      = (const float*)d_in[3];
  const float* lora_down = (const float*)d_in[4];
  const float* lora_up   = (const float*)d_in[5];
  const float* smooth    = (const float*)d_in[6];
  const float* norm_q    = (const float*)d_in[7];
  const float* norm_k    = (const float*)d_in[8];
  const float* rot       = (const float*)d_in[9];
  float* out = (float*)d_out;

  u16* Aex = (u16*)d_ws;                               // 4096*3136 bf16
  u16* Bex = Aex + (size_t)MDIM * KP;                  // 9216*3136 bf16

  k_prep<<<QB + WB + PB, 256, 0, stream>>>(x, qweight, wscales, lora_down, lora_up, smooth, Aex, Bex);
  k_gemm<<<dim3(NDIM / 128, MDIM / 128), 256, 0, stream>>>(Aex, Bex, bias, norm_q, norm_k, rot, out);
}